// Round 3
// baseline (2004.909 us; speedup 1.0000x reference)
//
#include <hip/hip_runtime.h>
#include <cstdint>

typedef _Float16 f16;
typedef _Float16 f16x2 __attribute__((ext_vector_type(2)));

#define T_STEPS 512
#define B_SZ 512
#define LOG2PI 1.8378770664093453f

__device__ __forceinline__ uint32_t packh2(float a, float b) {
  f16x2 v; v[0] = (f16)a; v[1] = (f16)b;
  return __builtin_bit_cast(uint32_t, v);
}

__device__ __forceinline__ float fdot2(uint32_t a, uint32_t b, float c) {
#if defined(__AMDGCN__) && __has_builtin(__builtin_amdgcn_fdot2)
  return __builtin_amdgcn_fdot2(__builtin_bit_cast(f16x2, a),
                                __builtin_bit_cast(f16x2, b), c, false);
#else
  f16x2 x = __builtin_bit_cast(f16x2, a), y = __builtin_bit_cast(f16x2, b);
  return c + (float)x[0] * (float)y[0] + (float)x[1] * (float)y[1];
#endif
}

#define DOT4(acc, w0, w1, w2, w3, v)                                     \
  do {                                                                   \
    acc = fdot2((w0), (v).x, acc); acc = fdot2((w1), (v).y, acc);        \
    acc = fdot2((w2), (v).z, acc); acc = fdot2((w3), (v).w, acc);        \
  } while (0)

__device__ __forceinline__ float sigmoidf_(float x) {
  return 1.0f / (1.0f + __expf(-x));
}
__device__ __forceinline__ float tanhf_(float x) {
  float ax = fabsf(x);
  float t = __expf(-2.0f * ax);
  float r = (1.0f - t) / (1.0f + t);
  return copysignf(r, x);
}
__device__ __forceinline__ float softplusf_(float x) {
  return fmaxf(x, 0.0f) + __logf(1.0f + __expf(-fabsf(x)));
}

// ---------------------------------------------------------------------------
// Kernel 1: embedding / state_t construction.  state_t: (T,B,32) f16.
// ---------------------------------------------------------------------------
__global__ __launch_bounds__(256) void k_embed(
    const float* __restrict__ xs, const float* __restrict__ shot_emb,
    const float* __restrict__ player_emb, f16* __restrict__ state_t,
    float* __restrict__ accums) {
  if (blockIdx.x == 0 && threadIdx.x < 16) accums[threadIdx.x] = 0.0f;
  size_t idx = (size_t)blockIdx.x * 256 + threadIdx.x;
  const float* xp = xs + idx * 23;
  f16* op = state_t + idx * 32;
  int sid = (int)xp[12];
  int pid = (int)xp[17];
#pragma unroll
  for (int i = 0; i < 12; ++i) op[i] = (f16)xp[i];
  const float* se = shot_emb + sid * 8;
#pragma unroll
  for (int i = 0; i < 8; ++i) op[12 + i] = (f16)se[i];
#pragma unroll
  for (int i = 0; i < 4; ++i) op[20 + i] = (f16)xp[13 + i];
  const float* pe = player_emb + pid * 8;
#pragma unroll
  for (int i = 0; i < 8; ++i) op[24 + i] = (f16)pe[i];
}

// ---------------------------------------------------------------------------
// Kernel 2: backward GRU scan + encoder + qz0 head.
// 512 blocks x 448 threads, 1 batch/block (2 blocks/CU). Weights in registers.
// tid<384: gate row tid (full K; R=0..127, Z=128..255, N=256..383)
// tid 384..447: enc row (full K) -> writes ctx directly to global
// 2 barriers per step.  __launch_bounds__(448,4): VGPR<=128 for 2 blocks/CU.
// ---------------------------------------------------------------------------
__global__ __launch_bounds__(448, 4) void k_gru(
    const f16* __restrict__ state_t, const float* __restrict__ wih,
    const float* __restrict__ whh, const float* __restrict__ bih,
    const float* __restrict__ bhh, const float* __restrict__ enc_w,
    const float* __restrict__ enc_b, const float* __restrict__ qz0_w,
    const float* __restrict__ qz0_b, const float* __restrict__ z0_noise,
    const float* __restrict__ pz0_mean, const float* __restrict__ pz0_logstd,
    f16* __restrict__ ctx, float* __restrict__ z0_out,
    float* __restrict__ accums) {
  __shared__ __align__(16) uint32_t s_x[16];   // x_t, f16x2 packed
  __shared__ __align__(16) uint32_t s_h[64];   // h,   f16x2 packed
  __shared__ float s_gi[384], s_gh[384];
  __shared__ float s_ctx0[64];
  __shared__ float s_q[32];

  const int tid = threadIdx.x;
  const int bg = blockIdx.x;
  const uint32_t* stu = (const uint32_t*)state_t;

  uint32_t wA[64];  // whh row | enc row
  uint32_t wB[16];  // wih row
  float bi = 0.f, bh = 0.f, encbr = 0.f;

  if (tid < 384) {
    const float* whr = whh + (size_t)tid * 128;
#pragma unroll
    for (int i = 0; i < 64; ++i) wA[i] = packh2(whr[2 * i], whr[2 * i + 1]);
    const float* wxr = wih + (size_t)tid * 32;
#pragma unroll
    for (int i = 0; i < 16; ++i) wB[i] = packh2(wxr[2 * i], wxr[2 * i + 1]);
    bi = bih[tid];
    bh = bhh[tid];
  } else {
    int cc = tid - 384;
    const float* wer = enc_w + (size_t)cc * 128;
#pragma unroll
    for (int i = 0; i < 64; ++i) wA[i] = packh2(wer[2 * i], wer[2 * i + 1]);
    encbr = enc_b[cc];
  }

  if (tid < 64) s_h[tid] = 0u;
  if (tid < 4)
    *(uint4*)&s_x[tid * 4] =
        *(const uint4*)(stu + ((size_t)(T_STEPS - 1) * B_SZ + bg) * 16 + tid * 4);
  float h_old = 0.0f;
  __syncthreads();

  for (int t = T_STEPS - 1; t >= 0; --t) {
    uint4 xpref = make_uint4(0, 0, 0, 0);
    if (tid >= 128 && tid < 132 && t > 0)
      xpref = *(const uint4*)(stu + ((size_t)(t - 1) * B_SZ + bg) * 16 +
                              (tid - 128) * 4);
    // ---- Phase A: gate dots + enc(h) -> ctx[t+1]
    if (tid < 384) {
      float ax0 = bi, ax1 = 0.f;
      const uint4* xq = (const uint4*)s_x;
#pragma unroll
      for (int j = 0; j < 4; ++j) {
        uint4 v = xq[j];
        if (j & 1) { DOT4(ax1, wB[4 * j], wB[4 * j + 1], wB[4 * j + 2], wB[4 * j + 3], v); }
        else       { DOT4(ax0, wB[4 * j], wB[4 * j + 1], wB[4 * j + 2], wB[4 * j + 3], v); }
      }
      float ah0 = bh, ah1 = 0.f;
      const uint4* hq = (const uint4*)s_h;
#pragma unroll
      for (int j = 0; j < 16; ++j) {
        uint4 v = hq[j];
        if (j & 1) { DOT4(ah1, wA[4 * j], wA[4 * j + 1], wA[4 * j + 2], wA[4 * j + 3], v); }
        else       { DOT4(ah0, wA[4 * j], wA[4 * j + 1], wA[4 * j + 2], wA[4 * j + 3], v); }
      }
      s_gi[tid] = ax0 + ax1;
      s_gh[tid] = ah0 + ah1;
    } else if (t < T_STEPS - 1) {
      int cc = tid - 384;
      float a0 = encbr, a1 = 0.f;
      const uint4* hq = (const uint4*)s_h;
#pragma unroll
      for (int j = 0; j < 16; ++j) {
        uint4 v = hq[j];
        if (j & 1) { DOT4(a1, wA[4 * j], wA[4 * j + 1], wA[4 * j + 2], wA[4 * j + 3], v); }
        else       { DOT4(a0, wA[4 * j], wA[4 * j + 1], wA[4 * j + 2], wA[4 * j + 3], v); }
      }
      ctx[((size_t)(t + 1) * B_SZ + bg) * 64 + cc] = (f16)(a0 + a1);
    }
    __syncthreads();
    // ---- Phase B: h update; x stage
    if (tid < 128) {
      float r = sigmoidf_(s_gi[tid] + s_gh[tid]);
      float zg = sigmoidf_(s_gi[128 + tid] + s_gh[128 + tid]);
      float n = tanhf_(s_gi[256 + tid] + r * s_gh[256 + tid]);
      float hnew = (1.0f - zg) * n + zg * h_old;
      h_old = hnew;
      ((f16*)s_h)[tid] = (f16)hnew;
    } else if (tid >= 128 && tid < 132 && t > 0) {
      *(uint4*)&s_x[(tid - 128) * 4] = xpref;
    }
    __syncthreads();
  }

  // ---- Tail: enc(h(0)) -> ctx[0] + s_ctx0; qz0; z0 + KL
  if (tid >= 384) {
    int cc = tid - 384;
    float a0 = encbr, a1 = 0.f;
    const uint4* hq = (const uint4*)s_h;
#pragma unroll
    for (int j = 0; j < 16; ++j) {
      uint4 v = hq[j];
      if (j & 1) { DOT4(a1, wA[4 * j], wA[4 * j + 1], wA[4 * j + 2], wA[4 * j + 3], v); }
      else       { DOT4(a0, wA[4 * j], wA[4 * j + 1], wA[4 * j + 2], wA[4 * j + 3], v); }
    }
    float val = a0 + a1;
    ctx[(size_t)bg * 64 + cc] = (f16)val;
    s_ctx0[cc] = val;
  }
  __syncthreads();
  if (tid < 32) {
    float acc = qz0_b[tid];
#pragma unroll 8
    for (int k = 0; k < 64; ++k) acc += qz0_w[tid * 64 + k] * s_ctx0[k];
    s_q[tid] = acc;
  }
  __syncthreads();
  if (tid < 16) {
    float qm = s_q[tid], qls = s_q[16 + tid];
    float z0v = qm + __expf(qls) * z0_noise[bg * 16 + tid];
    z0_out[bg * 16 + tid] = z0v;
    float pm = pz0_mean[tid], pls = pz0_logstd[tid];
    float var_q = __expf(2.0f * qls);
    float var_p = __expf(2.0f * pls);
    float dm = qm - pm;
    float kl = pls - qls + (var_q + dm * dm) / (2.0f * var_p) - 0.5f;
    atomicAdd(&accums[5], kl);
  }
}

// ---------------------------------------------------------------------------
// Kernel 3: SDE Euler-Maruyama scan. 512 blocks x 256 threads, 1 batch/block
// (2 blocks/CU). Weights register-resident; 4 barriers/step.
// A: tid<128 f1 row | tid>=128 h1 row + g-slice
// B: all 256: layer-2 full-K row (mlp=tid>>7, u=tid&127)
// C: all 256: layer-3 K-slice partial (mlp, o=tid&15, k8=(tid>>4)&7)
// D: tid<16 combine + z update | tid16..23 stage prefetched ctx
// ---------------------------------------------------------------------------
__global__ __launch_bounds__(256, 2) void k_sde(
    const f16* __restrict__ ctx, const float* __restrict__ z0_in,
    const float* __restrict__ ts, const float* __restrict__ bm_noise,
    const float* __restrict__ fw1, const float* __restrict__ fb1,
    const float* __restrict__ fw2, const float* __restrict__ fb2,
    const float* __restrict__ fw3, const float* __restrict__ fb3,
    const float* __restrict__ hw1, const float* __restrict__ hb1,
    const float* __restrict__ hw2, const float* __restrict__ hb2,
    const float* __restrict__ hw3, const float* __restrict__ hb3,
    const float* __restrict__ gw1, const float* __restrict__ gb1,
    const float* __restrict__ gw2, const float* __restrict__ gb2,
    f16* __restrict__ zs, float* __restrict__ accums) {
  __shared__ __align__(16) uint32_t s_x2[40];    // [z(8) | ctx(32)] f16x2
  __shared__ __align__(16) uint32_t s_h1f[64];   // f layer-1 act
  __shared__ __align__(16) uint32_t s_h1h[64];   // h layer-1 act
  __shared__ __align__(16) uint32_t s_h2[2][64]; // layer-2 act
  __shared__ float s_zf[16];
  __shared__ __align__(16) float s_gp[128];      // [l][k8]
  __shared__ __align__(16) float s_p3[256];      // [(mlp*16+o)*8+k8]
  __shared__ float s_dts[T_STEPS];

  const int tid = threadIdx.x;
  const int bg = blockIdx.x;

  uint32_t uw[56];   // f1: 40 wpacks | h1: 8 wpacks + g: 48 f32-bits
  uint32_t wP2[64];  // layer-2 full row
  uint32_t wP3[8];   // layer-3 K-slice
  float bias1r = 0.f, bias2r = 0.f, gb2r = 0.f, fb3r = 0.f, hb3r = 0.f;

  if (tid < 128) {
    const float* w = fw1 + (size_t)tid * 80;
#pragma unroll
    for (int i = 0; i < 40; ++i) uw[i] = packh2(w[2 * i], w[2 * i + 1]);
    bias1r = fb1[tid];
  } else {
    int u = tid - 128;
    const float* w = hw1 + (size_t)u * 16;
#pragma unroll
    for (int i = 0; i < 8; ++i) uw[i] = packh2(w[2 * i], w[2 * i + 1]);
    bias1r = hb1[u];
    int l = u & 15, k8 = u >> 4;
#pragma unroll
    for (int i = 0; i < 16; ++i) {
      int h = k8 * 16 + i;
      uw[8 + i] = __builtin_bit_cast(uint32_t, gw1[l * 128 + h]);
      uw[24 + i] = __builtin_bit_cast(uint32_t, gb1[l * 128 + h]);
      uw[40 + i] = __builtin_bit_cast(uint32_t, gw2[l * 128 + h]);
    }
  }
  {
    int mlp = tid >> 7, u = tid & 127;
    const float* w = (mlp ? hw2 : fw2) + (size_t)u * 128;
#pragma unroll
    for (int i = 0; i < 64; ++i) wP2[i] = packh2(w[2 * i], w[2 * i + 1]);
    bias2r = (mlp ? hb2 : fb2)[u];
  }
  {
    int mlp = tid >> 7, o = tid & 15, k8 = (tid >> 4) & 7;
    const float* w = (mlp ? hw3 : fw3) + (size_t)o * 128 + k8 * 16;
#pragma unroll
    for (int i = 0; i < 8; ++i) wP3[i] = packh2(w[2 * i], w[2 * i + 1]);
  }
  if (tid < 16) {
    fb3r = fb3[tid];
    hb3r = hb3[tid];
    gb2r = gb2[tid];
  }
  for (int i = tid; i < T_STEPS - 1; i += 256) s_dts[i] = ts[i + 1] - ts[i];

  if (tid < 16) {
    float z = z0_in[bg * 16 + tid];
    s_zf[tid] = z;
    ((f16*)s_x2)[tid] = (f16)z;
    zs[(size_t)bg * 16 + tid] = (f16)z;
  }
  if (tid >= 16 && tid < 24) {
    int q = tid - 16;
    *(uint4*)&s_x2[8 + q * 4] =
        *(const uint4*)((const uint32_t*)ctx + ((size_t)1 * B_SZ + bg) * 32 + q * 4);
  }
  float path_acc = 0.0f;
  __syncthreads();

  for (int t = 0; t < T_STEPS - 1; ++t) {
    float bm_cur = 0.f;
    uint4 cpref = make_uint4(0, 0, 0, 0);
    if (tid < 16) bm_cur = bm_noise[((size_t)t * B_SZ + bg) * 16 + tid];
    if (tid >= 16 && tid < 24 && t <= T_STEPS - 3) {
      int q = tid - 16;
      cpref = *(const uint4*)((const uint32_t*)ctx +
                              ((size_t)(t + 2) * B_SZ + bg) * 32 + q * 4);
    }
    // ---- A
    if (tid < 128) {
      float a0 = bias1r, a1 = 0.f;
      const uint4* xq = (const uint4*)s_x2;
#pragma unroll
      for (int j = 0; j < 10; ++j) {
        uint4 v = xq[j];
        if (j & 1) { DOT4(a1, uw[4 * j], uw[4 * j + 1], uw[4 * j + 2], uw[4 * j + 3], v); }
        else       { DOT4(a0, uw[4 * j], uw[4 * j + 1], uw[4 * j + 2], uw[4 * j + 3], v); }
      }
      ((f16*)s_h1f)[tid] = (f16)softplusf_(a0 + a1);
    } else {
      int u = tid - 128;
      const uint4* zq = (const uint4*)s_x2;
      float a0 = bias1r, a1 = 0.f;
      uint4 v0 = zq[0], v1 = zq[1];
      DOT4(a0, uw[0], uw[1], uw[2], uw[3], v0);
      DOT4(a1, uw[4], uw[5], uw[6], uw[7], v1);
      ((f16*)s_h1h)[u] = (f16)softplusf_(a0 + a1);
      int l = u & 15, k8 = u >> 4;
      float y = s_zf[l];
      float acc = 0.f;
#pragma unroll
      for (int i = 0; i < 16; ++i) {
        float pre = fmaf(y, __builtin_bit_cast(float, uw[8 + i]),
                         __builtin_bit_cast(float, uw[24 + i]));
        acc = fmaf(softplusf_(pre), __builtin_bit_cast(float, uw[40 + i]), acc);
      }
      s_gp[l * 8 + k8] = acc;
    }
    __syncthreads();
    // ---- B: layer-2 full-K rows
    {
      const uint4* hq = (const uint4*)((tid >> 7) ? s_h1h : s_h1f);
      float a0 = bias2r, a1 = 0.f, a2 = 0.f, a3 = 0.f;
#pragma unroll
      for (int j = 0; j < 16; j += 4) {
        uint4 v0 = hq[j], v1 = hq[j + 1], v2 = hq[j + 2], v3 = hq[j + 3];
        DOT4(a0, wP2[4 * j], wP2[4 * j + 1], wP2[4 * j + 2], wP2[4 * j + 3], v0);
        DOT4(a1, wP2[4 * j + 4], wP2[4 * j + 5], wP2[4 * j + 6], wP2[4 * j + 7], v1);
        DOT4(a2, wP2[4 * j + 8], wP2[4 * j + 9], wP2[4 * j + 10], wP2[4 * j + 11], v2);
        DOT4(a3, wP2[4 * j + 12], wP2[4 * j + 13], wP2[4 * j + 14], wP2[4 * j + 15], v3);
      }
      ((f16*)s_h2[tid >> 7])[tid & 127] = (f16)softplusf_((a0 + a1) + (a2 + a3));
    }
    __syncthreads();
    // ---- C: layer-3 partials
    {
      int mlp = tid >> 7, o = tid & 15, k8 = (tid >> 4) & 7;
      const uint4* hq = (const uint4*)&s_h2[mlp][k8 * 8];
      uint4 v0 = hq[0], v1 = hq[1];
      float a0 = 0.f, a1 = 0.f;
      DOT4(a0, wP3[0], wP3[1], wP3[2], wP3[3], v0);
      DOT4(a1, wP3[4], wP3[5], wP3[6], wP3[7], v1);
      s_p3[(mlp * 16 + o) * 8 + k8] = a0 + a1;
    }
    __syncthreads();
    // ---- D: combine + z update; ctx stage
    if (tid < 16) {
      int l = tid;
      const float4* fp = (const float4*)&s_p3[l * 8];
      const float4* hp = (const float4*)&s_p3[(16 + l) * 8];
      const float4* gp = (const float4*)&s_gp[l * 8];
      float4 f0 = fp[0], f1v = fp[1], h0 = hp[0], h1v = hp[1];
      float4 g0 = gp[0], g1 = gp[1];
      float fv = fb3r + ((f0.x + f0.y) + (f0.z + f0.w)) +
                 ((f1v.x + f1v.y) + (f1v.z + f1v.w));
      float hv = hb3r + ((h0.x + h0.y) + (h0.z + h0.w)) +
                 ((h1v.x + h1v.y) + (h1v.z + h1v.w));
      float gv = sigmoidf_(gb2r + ((g0.x + g0.y) + (g0.z + g0.w)) +
                           ((g1.x + g1.y) + (g1.z + g1.w)));
      float dt = s_dts[t];
      float u = (fv - hv) / gv;
      float lsum = u * u;
      lsum += __shfl_xor(lsum, 1);
      lsum += __shfl_xor(lsum, 2);
      lsum += __shfl_xor(lsum, 4);
      lsum += __shfl_xor(lsum, 8);
      if (l == 0) path_acc += 0.5f * lsum * dt;
      float zn = s_zf[l] + fv * dt + gv * (sqrtf(dt) * bm_cur);
      s_zf[l] = zn;
      ((f16*)s_x2)[l] = (f16)zn;
      zs[((size_t)(t + 1) * B_SZ + bg) * 16 + l] = (f16)zn;
    } else if (tid >= 16 && tid < 24 && t <= T_STEPS - 3) {
      int q = tid - 16;
      *(uint4*)&s_x2[8 + q * 4] = cpref;
    }
    __syncthreads();
  }
  if (tid == 0) atomicAdd(&accums[6], path_acc);
}

// ---------------------------------------------------------------------------
// Kernel 4: decoder + losses.  2 tokens per thread, uint4 LDS layouts.
// 512 blocks x 256 threads.
// ---------------------------------------------------------------------------
__global__ __launch_bounds__(256) void k_dec(
    const f16* __restrict__ zs, const f16* __restrict__ state_t,
    const float* __restrict__ xs, const float* __restrict__ proj_w,
    const float* __restrict__ proj_b, const float* __restrict__ act_w,
    const float* __restrict__ act_b, const float* __restrict__ land_w,
    const float* __restrict__ shot_w, const float* __restrict__ move_w,
    float* __restrict__ accums) {
  __shared__ __align__(16) uint32_t s_proj[32 * 8];  // [i][kp]
  __shared__ __align__(16) uint32_t s_act[128 * 8];  // [j][kp]
  __shared__ __align__(16) uint32_t s_head[128 * 8]; // [j][p]
  __shared__ float s_pb[32], s_ab[128];
  __shared__ float s_red[4 * 5];

  const int tid = threadIdx.x;
  if (tid < 256) {
    int i = tid >> 3, kp = tid & 7;
    s_proj[tid] = packh2(proj_w[i * 16 + 2 * kp], proj_w[i * 16 + 2 * kp + 1]);
  }
  for (int id = tid; id < 1024; id += 256) {
    int j = id >> 3, kp = id & 7;
    s_act[id] = packh2(act_w[j * 16 + 2 * kp], act_w[j * 16 + 2 * kp + 1]);
  }
  for (int id = tid; id < 1024; id += 256) {
    int j = id >> 3, p = id & 7;
    int h0 = 2 * p, h1 = 2 * p + 1;
    float w0 = (h0 < 2) ? land_w[h0 * 128 + j]
                        : (h0 < 14 ? shot_w[(h0 - 2) * 128 + j]
                                   : move_w[(h0 - 14) * 128 + j]);
    float w1 = (h1 < 2) ? land_w[h1 * 128 + j]
                        : (h1 < 14 ? shot_w[(h1 - 2) * 128 + j]
                                   : move_w[(h1 - 14) * 128 + j]);
    s_head[j * 8 + p] = packh2(w0, w1);
  }
  if (tid < 32) s_pb[tid] = proj_b[tid];
  if (tid < 128) s_ab[tid] = act_b[tid];
  __syncthreads();

  size_t idx0 = (size_t)blockIdx.x * 512 + tid;
  size_t idx1 = idx0 + 256;
  uint32_t zA[8], zB[8];
  {
    const uint4* za = (const uint4*)(zs + idx0 * 16);
    const uint4* zb = (const uint4*)(zs + idx1 * 16);
    uint4 a0 = za[0], a1 = za[1], b0 = zb[0], b1 = zb[1];
    zA[0] = a0.x; zA[1] = a0.y; zA[2] = a0.z; zA[3] = a0.w;
    zA[4] = a1.x; zA[5] = a1.y; zA[6] = a1.z; zA[7] = a1.w;
    zB[0] = b0.x; zB[1] = b0.y; zB[2] = b0.z; zB[3] = b0.w;
    zB[4] = b1.x; zB[5] = b1.y; zB[6] = b1.z; zB[7] = b1.w;
  }
  uint32_t stA[16], stB[16];
  {
    const uint4* sa = (const uint4*)(state_t + idx0 * 32);
    const uint4* sb = (const uint4*)(state_t + idx1 * 32);
#pragma unroll
    for (int q = 0; q < 4; ++q) {
      uint4 va = sa[q], vb = sb[q];
      stA[4 * q] = va.x; stA[4 * q + 1] = va.y; stA[4 * q + 2] = va.z; stA[4 * q + 3] = va.w;
      stB[4 * q] = vb.x; stB[4 * q + 1] = vb.y; stB[4 * q + 2] = vb.z; stB[4 * q + 3] = vb.w;
    }
  }

  float sqA = 0.0f, sqB = 0.0f;
#pragma unroll 4
  for (int i = 0; i < 32; ++i) {
    const uint4* pw = (const uint4*)&s_proj[i * 8];
    uint4 w0 = pw[0], w1 = pw[1];
    float aA = s_pb[i], aB = s_pb[i];
    DOT4(aA, w0.x, w0.y, w0.z, w0.w, *(const uint4*)&zA[0]);
    DOT4(aA, w1.x, w1.y, w1.z, w1.w, *(const uint4*)&zA[4]);
    DOT4(aB, w0.x, w0.y, w0.z, w0.w, *(const uint4*)&zB[0]);
    DOT4(aB, w1.x, w1.y, w1.z, w1.w, *(const uint4*)&zB[4]);
    f16x2 svA = __builtin_bit_cast(f16x2, stA[i >> 1]);
    f16x2 svB = __builtin_bit_cast(f16x2, stB[i >> 1]);
    float dA = (float)svA[i & 1] - aA;
    float dB = (float)svB[i & 1] - aB;
    sqA += dA * dA;
    sqB += dB * dB;
  }

  float hdA[16], hdB[16];
#pragma unroll
  for (int i = 0; i < 16; ++i) { hdA[i] = 0.0f; hdB[i] = 0.0f; }
#pragma unroll 2
  for (int j = 0; j < 128; ++j) {
    const uint4* aw = (const uint4*)&s_act[j * 8];
    uint4 w0 = aw[0], w1 = aw[1];
    float aA = s_ab[j], aB = s_ab[j];
    DOT4(aA, w0.x, w0.y, w0.z, w0.w, *(const uint4*)&zA[0]);
    DOT4(aA, w1.x, w1.y, w1.z, w1.w, *(const uint4*)&zA[4]);
    DOT4(aB, w0.x, w0.y, w0.z, w0.w, *(const uint4*)&zB[0]);
    DOT4(aB, w1.x, w1.y, w1.z, w1.w, *(const uint4*)&zB[4]);
    aA = fmaxf(aA, 0.0f);
    aB = fmaxf(aB, 0.0f);
    const uint4* hw = (const uint4*)&s_head[j * 8];
    uint4 h0 = hw[0], h1 = hw[1];
    uint32_t whu[8] = {h0.x, h0.y, h0.z, h0.w, h1.x, h1.y, h1.z, h1.w};
#pragma unroll
    for (int p = 0; p < 8; ++p) {
      f16x2 w = __builtin_bit_cast(f16x2, whu[p]);
      float w0f = (float)w[0], w1f = (float)w[1];
      hdA[2 * p] += w0f * aA;
      hdA[2 * p + 1] += w1f * aA;
      hdB[2 * p] += w0f * aB;
      hdB[2 * p + 1] += w1f * aB;
    }
  }

  float vals[5] = {sqA + sqB, 0.f, 0.f, 0.f, 0.f};
#pragma unroll
  for (int tok = 0; tok < 2; ++tok) {
    const float* hd = tok ? hdB : hdA;
    const float* xp = xs + (tok ? idx1 : idx0) * 23;
    float dl0 = hd[0] - xp[18], dl1 = hd[1] - xp[19];
    vals[1] += dl0 * dl0 + dl1 * dl1;
    float dm0 = hd[14] - xp[21], dm1 = hd[15] - xp[22];
    vals[2] += dm0 * dm0 + dm1 * dm1;
    int sid = (int)xp[20];
    float m = hd[2];
#pragma unroll
    for (int s = 1; s < 12; ++s) m = fmaxf(m, hd[2 + s]);
    float sume = 0.0f;
#pragma unroll
    for (int s = 0; s < 12; ++s) sume += __expf(hd[2 + s] - m);
    float lse = m + __logf(sume);
    float pl = 0.0f;
#pragma unroll
    for (int s = 0; s < 12; ++s)
      if (s == sid) pl = hd[2 + s];
    if (sid != 0) {
      vals[3] += pl - lse;
      vals[4] += 1.0f;
    }
  }
#pragma unroll
  for (int v = 0; v < 5; ++v) {
    float x = vals[v];
    for (int off = 1; off < 64; off <<= 1) x += __shfl_xor(x, off);
    vals[v] = x;
  }
  int lane = tid & 63, wv = tid >> 6;
  if (lane == 0) {
#pragma unroll
    for (int v = 0; v < 5; ++v) s_red[wv * 5 + v] = vals[v];
  }
  __syncthreads();
  if (tid == 0) {
#pragma unroll
    for (int v = 0; v < 5; ++v) {
      float s = s_red[v] + s_red[5 + v] + s_red[10 + v] + s_red[15 + v];
      atomicAdd(&accums[v], s);
    }
  }
}

// ---------------------------------------------------------------------------
// Kernel 5: finalize the two scalar outputs.
// ---------------------------------------------------------------------------
__global__ void k_fin(const float* __restrict__ accums,
                      const float* __restrict__ noise_std,
                      float* __restrict__ out) {
  if (threadIdx.x == 0 && blockIdx.x == 0) {
    float sd = noise_std[0];
    float log_pxs = -0.5f * accums[0] / (sd * sd * (float)B_SZ) -
                    (float)T_STEPS * 32.0f * (logf(sd) + 0.5f * LOG2PI);
    float land = accums[1] / (float)(T_STEPS * B_SZ * 2);
    float move = accums[2] / (float)(T_STEPS * B_SZ * 2);
    float shot = -accums[3] / fmaxf(accums[4], 1.0f);
    float out1 = accums[5] / (float)B_SZ + accums[6] / (float)B_SZ + land + shot + move;
    out[0] = log_pxs;
    out[1] = out1;
  }
}

// ---------------------------------------------------------------------------
extern "C" void kernel_launch(void* const* d_in, const int* in_sizes, int n_in,
                              void* d_out, int out_size, void* d_ws,
                              size_t ws_size, hipStream_t stream) {
  const float* xs = (const float*)d_in[1];
  const float* ts = (const float*)d_in[2];
  const float* noise_std = (const float*)d_in[3];
  const float* z0_noise = (const float*)d_in[4];
  const float* bm_noise = (const float*)d_in[5];
  const float* shot_emb = (const float*)d_in[6];
  const float* player_emb = (const float*)d_in[7];
  const float* gru_wih = (const float*)d_in[8];
  const float* gru_whh = (const float*)d_in[9];
  const float* gru_bih = (const float*)d_in[10];
  const float* gru_bhh = (const float*)d_in[11];
  const float* enc_w = (const float*)d_in[12];
  const float* enc_b = (const float*)d_in[13];
  const float* qz0_w = (const float*)d_in[14];
  const float* qz0_b = (const float*)d_in[15];
  const float* f_w1 = (const float*)d_in[16];
  const float* f_b1 = (const float*)d_in[17];
  const float* f_w2 = (const float*)d_in[18];
  const float* f_b2 = (const float*)d_in[19];
  const float* f_w3 = (const float*)d_in[20];
  const float* f_b3 = (const float*)d_in[21];
  const float* h_w1 = (const float*)d_in[22];
  const float* h_b1 = (const float*)d_in[23];
  const float* h_w2 = (const float*)d_in[24];
  const float* h_b2 = (const float*)d_in[25];
  const float* h_w3 = (const float*)d_in[26];
  const float* h_b3 = (const float*)d_in[27];
  const float* g_w1 = (const float*)d_in[28];
  const float* g_b1 = (const float*)d_in[29];
  const float* g_w2 = (const float*)d_in[30];
  const float* g_b2 = (const float*)d_in[31];
  const float* proj_w = (const float*)d_in[32];
  const float* proj_b = (const float*)d_in[33];
  const float* pz0_mean = (const float*)d_in[34];
  const float* pz0_logstd = (const float*)d_in[35];
  const float* act_w = (const float*)d_in[36];
  const float* act_b = (const float*)d_in[37];
  const float* act_land_w = (const float*)d_in[38];
  const float* act_shot_w = (const float*)d_in[39];
  const float* act_move_w = (const float*)d_in[40];

  char* ws = (char*)d_ws;
  float* accums = (float*)ws;                       // 16 floats (256 B reserved)
  f16* state_t = (f16*)(ws + 256);                  // T*B*32 f16 = 16 MB
  f16* ctx = (f16*)(ws + 256 + 16777216);           // T*B*64 f16 = 32 MB
  float* z0b = (float*)(ws + 256 + 16777216 + 33554432);   // B*16 f32
  f16* zs = (f16*)(ws + 256 + 16777216 + 33554432 + 32768);  // T*B*16 f16 = 8 MB

  k_embed<<<1024, 256, 0, stream>>>(xs, shot_emb, player_emb, state_t, accums);
  k_gru<<<512, 448, 0, stream>>>(state_t, gru_wih, gru_whh, gru_bih, gru_bhh,
                                 enc_w, enc_b, qz0_w, qz0_b, z0_noise, pz0_mean,
                                 pz0_logstd, ctx, z0b, accums);
  k_sde<<<512, 256, 0, stream>>>(ctx, z0b, ts, bm_noise, f_w1, f_b1, f_w2, f_b2,
                                 f_w3, f_b3, h_w1, h_b1, h_w2, h_b2, h_w3, h_b3,
                                 g_w1, g_b1, g_w2, g_b2, zs, accums);
  k_dec<<<512, 256, 0, stream>>>(zs, state_t, xs, proj_w, proj_b, act_w, act_b,
                                 act_land_w, act_shot_w, act_move_w, accums);
  k_fin<<<1, 64, 0, stream>>>(accums, noise_std, (float*)d_out);
}